// Round 1
// baseline (235.704 us; speedup 1.0000x reference)
//
#include <hip/hip_runtime.h>
#include <math.h>

#define EPS 1e-8f

// One wave (64 lanes) per token (f,i). Fused: reads row a = x[f,i] and the two
// partner rows b1 = x[f+interval, i+1], b2 = x[f+interval, i+width] once,
// accumulating ||a||^2, ||b1||^2, ||b2||^2, a.b1, a.b2 in a single pass.
// float4 coalesced loads (hidden=1152 -> 288 vec4, 16B-aligned rows).
// Validity predicates are wave-uniform -> no divergence.
__global__ void __launch_bounds__(256) simdiff_kernel(
    const float* __restrict__ x,
    const int* __restrict__ p_frames,
    const int* __restrict__ p_width,
    const int* __restrict__ p_interval,
    float* __restrict__ out,
    int ntok, int hidden)
{
    const int frames   = *p_frames;
    const int width    = *p_width;
    const int interval = *p_interval;
    const int tpf      = ntok / frames;
    const int valid_f  = frames - interval;

    const int lane            = threadIdx.x & 63;
    const int wave_in_block   = threadIdx.x >> 6;
    const int waves_per_block = blockDim.x >> 6;
    const int stride          = gridDim.x * waves_per_block;
    const int nvec            = hidden >> 2;  // float4 per row

    for (int task = blockIdx.x * waves_per_block + wave_in_block;
         task < ntok; task += stride) {
        const int f = task / tpf;
        const int i = task - f * tpf;

        const bool rv = (f < valid_f) && (i < tpf - 1);      // right valid
        const bool dv = (f < valid_f) && (i < tpf - width);  // down  valid

        float out_r = -1.0f, out_d = -1.0f;

        if (rv || dv) {
            const float4* __restrict__ A =
                (const float4*)(x + (size_t)task * hidden);
            const float4* __restrict__ B1 = rv
                ? (const float4*)(x + (size_t)((f + interval) * tpf + i + 1) * hidden)
                : (const float4*)A;
            const float4* __restrict__ B2 = dv
                ? (const float4*)(x + (size_t)((f + interval) * tpf + i + width) * hidden)
                : (const float4*)A;

            float na2 = 0.f, nb1 = 0.f, nb2 = 0.f, d1 = 0.f, d2 = 0.f;

            for (int v = lane; v < nvec; v += 64) {
                const float4 a = A[v];
                na2 = fmaf(a.x, a.x, fmaf(a.y, a.y, fmaf(a.z, a.z, fmaf(a.w, a.w, na2))));
                if (rv) {
                    const float4 b = B1[v];
                    nb1 = fmaf(b.x, b.x, fmaf(b.y, b.y, fmaf(b.z, b.z, fmaf(b.w, b.w, nb1))));
                    d1  = fmaf(a.x, b.x, fmaf(a.y, b.y, fmaf(a.z, b.z, fmaf(a.w, b.w, d1))));
                }
                if (dv) {
                    const float4 c = B2[v];
                    nb2 = fmaf(c.x, c.x, fmaf(c.y, c.y, fmaf(c.z, c.z, fmaf(c.w, c.w, nb2))));
                    d2  = fmaf(a.x, c.x, fmaf(a.y, c.y, fmaf(a.z, c.z, fmaf(a.w, c.w, d2))));
                }
            }

            // 64-lane butterfly reduction over the 5 accumulators.
            #pragma unroll
            for (int m = 1; m < 64; m <<= 1) {
                na2 += __shfl_xor(na2, m, 64);
                nb1 += __shfl_xor(nb1, m, 64);
                nb2 += __shfl_xor(nb2, m, 64);
                d1  += __shfl_xor(d1, m, 64);
                d2  += __shfl_xor(d2, m, 64);
            }

            const float na = fmaxf(sqrtf(na2), EPS);
            if (rv) out_r = d1 / (na * fmaxf(sqrtf(nb1), EPS));
            if (dv) out_d = d2 / (na * fmaxf(sqrtf(nb2), EPS));
        }

        if (lane == 0) {
            out[task]        = out_r;  // right_full
            out[ntok + task] = out_d;  // down_full
        }
    }
}

extern "C" void kernel_launch(void* const* d_in, const int* in_sizes, int n_in,
                              void* d_out, int out_size, void* d_ws, size_t ws_size,
                              hipStream_t stream) {
    const float* x        = (const float*)d_in[0];
    const int* p_frames   = (const int*)d_in[1];
    // d_in[2] = height (unused; tpf derived from ntok/frames)
    const int* p_width    = (const int*)d_in[3];
    const int* p_interval = (const int*)d_in[4];
    float* out            = (float*)d_out;

    const int ntok   = out_size / 2;          // frames * tpf = 35328
    const int hidden = in_sizes[0] / ntok;    // 1152

    const int threads         = 256;
    const int waves_per_block = threads / 64;
    const int blocks          = (ntok + waves_per_block - 1) / waves_per_block;

    simdiff_kernel<<<blocks, threads, 0, stream>>>(
        x, p_frames, p_width, p_interval, out, ntok, hidden);
}

// Round 2
// 224.763 us; speedup vs baseline: 1.0487x; 1.0487x over previous
//
#include <hip/hip_runtime.h>
#include <math.h>

#define EPS 1e-8f

// Specialized for hidden == 1152: each row = 288 float4 = 4*64 float4 + 64 float2
// per 64-lane wave. All 15 loads (3 rows x 5) are issued up-front, fully
// independent, so memory latency is overlapped instead of serialized.
__global__ void __launch_bounds__(256) simdiff_1152_kernel(
    const float* __restrict__ x,
    const int* __restrict__ p_frames,
    const int* __restrict__ p_width,
    const int* __restrict__ p_interval,
    float* __restrict__ out,
    int ntok)
{
    const int frames   = *p_frames;
    const int width    = *p_width;
    const int interval = *p_interval;
    const int tpf      = ntok / frames;
    const int valid_f  = frames - interval;

    const int lane = threadIdx.x & 63;
    const int task = blockIdx.x * (blockDim.x >> 6) + (threadIdx.x >> 6);
    if (task >= ntok) return;

    const int f = task / tpf;
    const int i = task - f * tpf;

    const bool rv = (f < valid_f) && (i < tpf - 1);      // right valid
    const bool dv = (f < valid_f) && (i < tpf - width);  // down  valid

    float out_r = -1.0f, out_d = -1.0f;

    if (rv || dv) {
        const float* A  = x + (size_t)task * 1152;
        const float* B1 = rv ? x + (size_t)((f + interval) * tpf + i + 1) * 1152     : A;
        const float* B2 = dv ? x + (size_t)((f + interval) * tpf + i + width) * 1152 : A;

        const float4* A4  = (const float4*)A;
        const float4* B14 = (const float4*)B1;
        const float4* B24 = (const float4*)B2;
        const float2* A2  = (const float2*)(A  + 1024);
        const float2* B12 = (const float2*)(B1 + 1024);
        const float2* B22 = (const float2*)(B2 + 1024);

        // ---- issue all 15 independent loads ----
        const float4 a0 = A4[lane];       const float4 a1 = A4[lane + 64];
        const float4 a2 = A4[lane + 128]; const float4 a3 = A4[lane + 192];
        const float2 a4 = A2[lane];

        const float4 p0 = B14[lane];       const float4 p1 = B14[lane + 64];
        const float4 p2 = B14[lane + 128]; const float4 p3 = B14[lane + 192];
        const float2 p4 = B12[lane];

        const float4 q0 = B24[lane];       const float4 q1 = B24[lane + 64];
        const float4 q2 = B24[lane + 128]; const float4 q3 = B24[lane + 192];
        const float2 q4 = B22[lane];

        // ---- accumulate ----
        float na2 = 0.f, nb1 = 0.f, nb2 = 0.f, d1 = 0.f, d2 = 0.f;

        #define ACC4(v)  na2 = fmaf(v.x,v.x, fmaf(v.y,v.y, fmaf(v.z,v.z, fmaf(v.w,v.w, na2))))
        #define NB14(v)  nb1 = fmaf(v.x,v.x, fmaf(v.y,v.y, fmaf(v.z,v.z, fmaf(v.w,v.w, nb1))))
        #define NB24(v)  nb2 = fmaf(v.x,v.x, fmaf(v.y,v.y, fmaf(v.z,v.z, fmaf(v.w,v.w, nb2))))
        #define DOT14(a,b) d1 = fmaf(a.x,b.x, fmaf(a.y,b.y, fmaf(a.z,b.z, fmaf(a.w,b.w, d1))))
        #define DOT24(a,b) d2 = fmaf(a.x,b.x, fmaf(a.y,b.y, fmaf(a.z,b.z, fmaf(a.w,b.w, d2))))

        ACC4(a0); ACC4(a1); ACC4(a2); ACC4(a3);
        na2 = fmaf(a4.x, a4.x, fmaf(a4.y, a4.y, na2));

        NB14(p0); NB14(p1); NB14(p2); NB14(p3);
        nb1 = fmaf(p4.x, p4.x, fmaf(p4.y, p4.y, nb1));
        DOT14(a0, p0); DOT14(a1, p1); DOT14(a2, p2); DOT14(a3, p3);
        d1 = fmaf(a4.x, p4.x, fmaf(a4.y, p4.y, d1));

        NB24(q0); NB24(q1); NB24(q2); NB24(q3);
        nb2 = fmaf(q4.x, q4.x, fmaf(q4.y, q4.y, nb2));
        DOT24(a0, q0); DOT24(a1, q1); DOT24(a2, q2); DOT24(a3, q3);
        d2 = fmaf(a4.x, q4.x, fmaf(a4.y, q4.y, d2));

        // ---- 64-lane butterfly over 5 accumulators ----
        #pragma unroll
        for (int m = 1; m < 64; m <<= 1) {
            na2 += __shfl_xor(na2, m, 64);
            nb1 += __shfl_xor(nb1, m, 64);
            nb2 += __shfl_xor(nb2, m, 64);
            d1  += __shfl_xor(d1, m, 64);
            d2  += __shfl_xor(d2, m, 64);
        }

        const float na = fmaxf(sqrtf(na2), EPS);
        if (rv) out_r = d1 / (na * fmaxf(sqrtf(nb1), EPS));
        if (dv) out_d = d2 / (na * fmaxf(sqrtf(nb2), EPS));
    }

    if (lane == 0) {
        out[task]        = out_r;
        out[ntok + task] = out_d;
    }
}

// Generic fallback (any hidden), the round-1 kernel.
__global__ void __launch_bounds__(256) simdiff_generic_kernel(
    const float* __restrict__ x,
    const int* __restrict__ p_frames,
    const int* __restrict__ p_width,
    const int* __restrict__ p_interval,
    float* __restrict__ out,
    int ntok, int hidden)
{
    const int frames   = *p_frames;
    const int width    = *p_width;
    const int interval = *p_interval;
    const int tpf      = ntok / frames;
    const int valid_f  = frames - interval;

    const int lane            = threadIdx.x & 63;
    const int wave_in_block   = threadIdx.x >> 6;
    const int waves_per_block = blockDim.x >> 6;
    const int stride          = gridDim.x * waves_per_block;
    const int nvec            = hidden >> 2;

    for (int task = blockIdx.x * waves_per_block + wave_in_block;
         task < ntok; task += stride) {
        const int f = task / tpf;
        const int i = task - f * tpf;
        const bool rv = (f < valid_f) && (i < tpf - 1);
        const bool dv = (f < valid_f) && (i < tpf - width);
        float out_r = -1.0f, out_d = -1.0f;

        if (rv || dv) {
            const float4* A  = (const float4*)(x + (size_t)task * hidden);
            const float4* B1 = rv ? (const float4*)(x + (size_t)((f + interval) * tpf + i + 1) * hidden) : A;
            const float4* B2 = dv ? (const float4*)(x + (size_t)((f + interval) * tpf + i + width) * hidden) : A;
            float na2 = 0.f, nb1 = 0.f, nb2 = 0.f, d1 = 0.f, d2 = 0.f;
            for (int v = lane; v < nvec; v += 64) {
                const float4 a = A[v];
                na2 = fmaf(a.x,a.x, fmaf(a.y,a.y, fmaf(a.z,a.z, fmaf(a.w,a.w, na2))));
                const float4 b = B1[v];
                nb1 = fmaf(b.x,b.x, fmaf(b.y,b.y, fmaf(b.z,b.z, fmaf(b.w,b.w, nb1))));
                d1  = fmaf(a.x,b.x, fmaf(a.y,b.y, fmaf(a.z,b.z, fmaf(a.w,b.w, d1))));
                const float4 c = B2[v];
                nb2 = fmaf(c.x,c.x, fmaf(c.y,c.y, fmaf(c.z,c.z, fmaf(c.w,c.w, nb2))));
                d2  = fmaf(a.x,c.x, fmaf(a.y,c.y, fmaf(a.z,c.z, fmaf(a.w,c.w, d2))));
            }
            #pragma unroll
            for (int m = 1; m < 64; m <<= 1) {
                na2 += __shfl_xor(na2, m, 64);
                nb1 += __shfl_xor(nb1, m, 64);
                nb2 += __shfl_xor(nb2, m, 64);
                d1  += __shfl_xor(d1, m, 64);
                d2  += __shfl_xor(d2, m, 64);
            }
            const float na = fmaxf(sqrtf(na2), EPS);
            if (rv) out_r = d1 / (na * fmaxf(sqrtf(nb1), EPS));
            if (dv) out_d = d2 / (na * fmaxf(sqrtf(nb2), EPS));
        }
        if (lane == 0) {
            out[task]        = out_r;
            out[ntok + task] = out_d;
        }
    }
}

extern "C" void kernel_launch(void* const* d_in, const int* in_sizes, int n_in,
                              void* d_out, int out_size, void* d_ws, size_t ws_size,
                              hipStream_t stream) {
    const float* x        = (const float*)d_in[0];
    const int* p_frames   = (const int*)d_in[1];
    const int* p_width    = (const int*)d_in[3];
    const int* p_interval = (const int*)d_in[4];
    float* out            = (float*)d_out;

    const int ntok   = out_size / 2;
    const int hidden = in_sizes[0] / ntok;

    const int threads         = 256;
    const int waves_per_block = threads / 64;
    const int blocks          = (ntok + waves_per_block - 1) / waves_per_block;

    if (hidden == 1152) {
        simdiff_1152_kernel<<<blocks, threads, 0, stream>>>(
            x, p_frames, p_width, p_interval, out, ntok);
    } else {
        simdiff_generic_kernel<<<blocks, threads, 0, stream>>>(
            x, p_frames, p_width, p_interval, out, ntok, hidden);
    }
}